// Round 1
// baseline (644.548 us; speedup 1.0000x reference)
//
#include <hip/hip_runtime.h>
#include <hip/hip_bf16.h>

#define HIDDEN 768
#define HEADS 12
#define HEAD_DIM 64
#define BATCH 128
#define SEQ 196
#define M_TOT (BATCH * SEQ)   /* 25088 */
#define QKV_N (3 * HIDDEN)    /* 2304  */

typedef __attribute__((ext_vector_type(8))) short bf16x8;
typedef __attribute__((ext_vector_type(4))) float f32x4;

// round-to-nearest-even f32 -> bf16 (bit pattern)
__device__ __forceinline__ unsigned short f2bf(float f) {
    unsigned int u = __builtin_bit_cast(unsigned int, f);
    unsigned int r = (u + 0x7fffu + ((u >> 16) & 1u)) >> 16;
    return (unsigned short)r;
}

__device__ __forceinline__ ushort4 cvt4(float4 v) {
    ushort4 o;
    o.x = f2bf(v.x); o.y = f2bf(v.y); o.z = f2bf(v.z); o.w = f2bf(v.w);
    return o;
}

// ---------------------------------------------------------------------------
// prep: cast x -> bf16; build fused Wqkv [2304,768] bf16 (rows: Wq|Wk|Wv);
// cast Wp -> bf16; fuse biases [2304] f32.
// ---------------------------------------------------------------------------
__global__ __launch_bounds__(256) void prep_kernel(
    const float* __restrict__ x,
    const float* __restrict__ Wq, const float* __restrict__ Wk,
    const float* __restrict__ Wv, const float* __restrict__ Wp,
    const float* __restrict__ bq, const float* __restrict__ bk,
    const float* __restrict__ bv,
    unsigned short* __restrict__ xb, unsigned short* __restrict__ wqkv,
    unsigned short* __restrict__ wpb, float* __restrict__ biasq)
{
    const long long NX = (long long)M_TOT * HIDDEN / 4;        // 4816896
    const long long NQ = NX + (long long)QKV_N * HIDDEN / 4;   // +442368
    const long long NP = NQ + (long long)HIDDEN * HIDDEN / 4;  // +147456
    const long long NB = NP + QKV_N / 4;                       // +576
    long long tid = (long long)blockIdx.x * 256 + threadIdx.x;
    if (tid < NX) {
        float4 v = ((const float4*)x)[tid];
        ((ushort4*)xb)[tid] = cvt4(v);
    } else if (tid < NQ) {
        int i = (int)(tid - NX);
        int e = i * 4;
        int row = e / HIDDEN, col = e % HIDDEN;
        const float* s = (row < HIDDEN) ? (Wq + (size_t)row * HIDDEN + col)
                       : (row < 2 * HIDDEN) ? (Wk + (size_t)(row - HIDDEN) * HIDDEN + col)
                       : (Wv + (size_t)(row - 2 * HIDDEN) * HIDDEN + col);
        ((ushort4*)wqkv)[i] = cvt4(*(const float4*)s);
    } else if (tid < NP) {
        int i = (int)(tid - NQ);
        ((ushort4*)wpb)[i] = cvt4(((const float4*)Wp)[i]);
    } else if (tid < NB) {
        int i = (int)(tid - NP);
        int e = i * 4;
        const float* s = (e < HIDDEN) ? (bq + e)
                       : (e < 2 * HIDDEN) ? (bk + (e - HIDDEN))
                       : (bv + (e - 2 * HIDDEN));
        *(float4*)(biasq + e) = *(const float4*)s;
    }
}

// ---------------------------------------------------------------------------
// m97-style GEMM: C[M,Ncols] = A[M,768] * B[Ncols,768]^T + bias
// 128x128 tile, BK=32, 16x16x32 bf16 MFMA, 4 waves each doing 64x64 (4x4 acc),
// global_load_lds width-16 staging. M, Ncols, K all exact multiples.
// ---------------------------------------------------------------------------
template <bool OUT_BF16>
__global__ __launch_bounds__(256) void gemm_bt(
    const unsigned short* __restrict__ A,
    const unsigned short* __restrict__ B,
    const float* __restrict__ bias,
    void* __restrict__ C, const int Ncols)
{
    constexpr int K = HIDDEN;
    __shared__ __align__(16) unsigned short As[128 * 32];
    __shared__ __align__(16) unsigned short Bs[128 * 32];
    const int t = threadIdx.x, w = t >> 6, lane = t & 63;
    const int m0 = blockIdx.y * 128, n0 = blockIdx.x * 128;
    const int wm = w >> 1, wn = w & 1;
    const int srow = lane >> 2, scol = (lane & 3) * 8;
    f32x4 acc[4][4] = {};
    const unsigned short* ag0 = A + (size_t)(m0 + w * 16 + srow) * K + scol;
    const unsigned short* bg0 = B + (size_t)(n0 + w * 16 + srow) * K + scol;
    const int l15 = lane & 15, q8 = (lane >> 4) * 8;

    for (int k0 = 0; k0 < K; k0 += 32) {
#pragma unroll
        for (int it = 0; it < 2; ++it) {
            __builtin_amdgcn_global_load_lds(
                (__attribute__((address_space(1))) void*)(ag0 + (size_t)it * 64 * K + k0),
                (__attribute__((address_space(3))) void*)(As + it * 2048 + w * 512),
                16, 0, 0);
            __builtin_amdgcn_global_load_lds(
                (__attribute__((address_space(1))) void*)(bg0 + (size_t)it * 64 * K + k0),
                (__attribute__((address_space(3))) void*)(Bs + it * 2048 + w * 512),
                16, 0, 0);
        }
        __syncthreads();
        bf16x8 af[4], bfv[4];
#pragma unroll
        for (int i = 0; i < 4; ++i) {
            af[i]  = *(const bf16x8*)(As + (wm * 64 + i * 16 + l15) * 32 + q8);
            bfv[i] = *(const bf16x8*)(Bs + (wn * 64 + i * 16 + l15) * 32 + q8);
        }
#pragma unroll
        for (int i = 0; i < 4; ++i)
#pragma unroll
            for (int j = 0; j < 4; ++j)
                acc[i][j] = __builtin_amdgcn_mfma_f32_16x16x32_bf16(af[i], bfv[j], acc[i][j], 0, 0, 0);
        __syncthreads();
    }

    const int quad = lane >> 4;
#pragma unroll
    for (int j = 0; j < 4; ++j) {
        const int c = n0 + wn * 64 + j * 16 + l15;
        const float bv = bias[c];
#pragma unroll
        for (int i = 0; i < 4; ++i) {
            const int r0 = m0 + wm * 64 + i * 16 + quad * 4;
#pragma unroll
            for (int r = 0; r < 4; ++r) {
                float v = acc[i][j][r] + bv;
                size_t idx = (size_t)(r0 + r) * Ncols + c;
                if constexpr (OUT_BF16) ((unsigned short*)C)[idx] = f2bf(v);
                else                    ((float*)C)[idx] = v;
            }
        }
    }
}

// ---------------------------------------------------------------------------
// attention: one block per (b,h). 4 waves; wave w owns Q row-tiles {w, w+4, ...}
// of 13 tiles (196 rows padded to 208). QK^T and PV via 16x16x32 bf16 MFMA.
// Q/K fragments read directly from global (L1-hot, 25 KB per head).
// V staged transposed in LDS (Vt[d][key], stride 224). P goes through per-wave
// LDS to convert C-layout -> A-layout. -1e30 sentinel (no NaNs anywhere).
// ---------------------------------------------------------------------------
__global__ __launch_bounds__(256) void attn_kernel(
    const unsigned short* __restrict__ QKV,
    const float* __restrict__ pos_bias,
    const int* __restrict__ mask,
    unsigned short* __restrict__ ctx)
{
    __shared__ __align__(16) unsigned short Vt[64 * 224];      // 28672 B
    __shared__ __align__(16) unsigned short Ps[4][16 * 224];   // 28672 B
    const int b = blockIdx.x / HEADS, h = blockIdx.x % HEADS;
    const int t = threadIdx.x, w = t >> 6, lane = t & 63;
    const int quad = lane >> 4, l15 = lane & 15;
    const size_t base = (size_t)b * SEQ * QKV_N + h * HEAD_DIM;

    // zero Vt pad columns (keys 196..223) so padded-K MFMA reads are clean 0s
    for (int i = t; i < 64 * 28; i += 256) {
        int d = i / 28, k = SEQ + (i % 28);
        Vt[d * 224 + k] = 0;
    }
    // stage V transposed: Vt[d][key] = V[key][d]
    for (int c = t; c < SEQ * HEAD_DIM / 8; c += 256) {
        int key = c >> 3, d0 = (c & 7) * 8;
        bf16x8 vv = *(const bf16x8*)(QKV + base + (size_t)key * QKV_N + 2 * HIDDEN + d0);
#pragma unroll
        for (int j = 0; j < 8; ++j)
            Vt[(d0 + j) * 224 + key] = (unsigned short)vv[j];
    }
    __syncthreads();

    for (int t16 = w; t16 < 13; t16 += 4) {
        // Q A-fragments: row = t16*16 + (lane&15), k = quad*8 + j (+32 for kt=1)
        const int qrow = min(t16 * 16 + l15, SEQ - 1);
        const unsigned short* qp = QKV + base + (size_t)qrow * QKV_N + quad * 8;
        bf16x8 qf0 = *(const bf16x8*)(qp);
        bf16x8 qf1 = *(const bf16x8*)(qp + 32);

        f32x4 acc[13];
#pragma unroll
        for (int jt = 0; jt < 13; ++jt) {
            const int krow = min(jt * 16 + l15, SEQ - 1);
            const unsigned short* kp = QKV + base + (size_t)krow * QKV_N + HIDDEN + quad * 8;
            bf16x8 kf0 = *(const bf16x8*)(kp);
            bf16x8 kf1 = *(const bf16x8*)(kp + 32);
            f32x4 z = {};
            z = __builtin_amdgcn_mfma_f32_16x16x32_bf16(qf0, kf0, z, 0, 0, 0);
            z = __builtin_amdgcn_mfma_f32_16x16x32_bf16(qf1, kf1, z, 0, 0, 0);
            acc[jt] = z;
        }

        // logits + row max (C layout: col = jt*16 + l15, row = t16*16 + quad*4 + r)
        float mx[4] = {-3e38f, -3e38f, -3e38f, -3e38f};
#pragma unroll
        for (int jt = 0; jt < 13; ++jt) {
            const int colk = jt * 16 + l15;
            const int mcol = min(colk, SEQ - 1);
            const bool cv = (colk < SEQ) && (mask[b * SEQ + mcol] != 0);
#pragma unroll
            for (int r = 0; r < 4; ++r) {
                const int row = t16 * 16 + quad * 4 + r;
                const float pb = pos_bias[(size_t)min(row, SEQ - 1) * SEQ + mcol];
                float v = cv ? (acc[jt][r] * 0.125f + pb) : -1e30f;
                acc[jt][r] = v;
                mx[r] = fmaxf(mx[r], v);
            }
        }
#pragma unroll
        for (int r = 0; r < 4; ++r) {
            mx[r] = fmaxf(mx[r], __shfl_xor(mx[r], 1, 16));
            mx[r] = fmaxf(mx[r], __shfl_xor(mx[r], 2, 16));
            mx[r] = fmaxf(mx[r], __shfl_xor(mx[r], 4, 16));
            mx[r] = fmaxf(mx[r], __shfl_xor(mx[r], 8, 16));
        }
        float sm[4] = {0.f, 0.f, 0.f, 0.f};
#pragma unroll
        for (int jt = 0; jt < 13; ++jt)
#pragma unroll
            for (int r = 0; r < 4; ++r) {
                float e = __expf(acc[jt][r] - mx[r]);
                acc[jt][r] = e;
                sm[r] += e;
            }
#pragma unroll
        for (int r = 0; r < 4; ++r) {
            sm[r] += __shfl_xor(sm[r], 1, 16);
            sm[r] += __shfl_xor(sm[r], 2, 16);
            sm[r] += __shfl_xor(sm[r], 4, 16);
            sm[r] += __shfl_xor(sm[r], 8, 16);
            sm[r] = 1.0f / sm[r];
        }
        // P -> per-wave LDS (C-layout write), pad cols 208..223 with zeros
#pragma unroll
        for (int jt = 0; jt < 13; ++jt)
#pragma unroll
            for (int r = 0; r < 4; ++r)
                Ps[w][(quad * 4 + r) * 224 + jt * 16 + l15] = f2bf(acc[jt][r] * sm[r]);
#pragma unroll
        for (int r = 0; r < 4; ++r)
            Ps[w][(quad * 4 + r) * 224 + 208 + l15] = 0;

        // PV: A-frag from Ps (row = l15, k contiguous), B-frag from Vt
        f32x4 o[4] = {};
#pragma unroll
        for (int kt = 0; kt < 7; ++kt) {
            bf16x8 pf = *(const bf16x8*)(&Ps[w][l15 * 224 + kt * 32 + quad * 8]);
#pragma unroll
            for (int nt = 0; nt < 4; ++nt) {
                bf16x8 vf = *(const bf16x8*)(&Vt[(nt * 16 + l15) * 224 + kt * 32 + quad * 8]);
                o[nt] = __builtin_amdgcn_mfma_f32_16x16x32_bf16(pf, vf, o[nt], 0, 0, 0);
            }
        }
        // store ctx[b*196+row][h*64 + d]
#pragma unroll
        for (int nt = 0; nt < 4; ++nt)
#pragma unroll
            for (int r = 0; r < 4; ++r) {
                const int row = t16 * 16 + quad * 4 + r;
                if (row < SEQ)
                    ctx[((size_t)b * SEQ + row) * HIDDEN + h * HEAD_DIM + nt * 16 + l15] =
                        f2bf(o[nt][r]);
            }
    }
}

// ---------------------------------------------------------------------------
extern "C" void kernel_launch(void* const* d_in, const int* in_sizes, int n_in,
                              void* d_out, int out_size, void* d_ws, size_t ws_size,
                              hipStream_t stream) {
    const float* x    = (const float*)d_in[0];
    const float* Wq   = (const float*)d_in[1];
    const float* bq   = (const float*)d_in[2];
    const float* Wk   = (const float*)d_in[3];
    const float* bk   = (const float*)d_in[4];
    const float* Wv   = (const float*)d_in[5];
    const float* bv   = (const float*)d_in[6];
    const float* Wp   = (const float*)d_in[7];
    const float* bp   = (const float*)d_in[8];
    const float* pos  = (const float*)d_in[9];
    const int*   mask = (const int*)d_in[10];

    char* ws = (char*)d_ws;
    size_t off = 0;
    auto alloc = [&](size_t bytes) -> char* {
        char* p = ws + off;
        off += (bytes + 255) & ~(size_t)255;
        return p;
    };
    unsigned short* xb    = (unsigned short*)alloc((size_t)M_TOT * HIDDEN * 2);
    unsigned short* wqkv  = (unsigned short*)alloc((size_t)QKV_N * HIDDEN * 2);
    unsigned short* wpb   = (unsigned short*)alloc((size_t)HIDDEN * HIDDEN * 2);
    float*          biasq = (float*)alloc((size_t)QKV_N * 4);
    unsigned short* qkv   = (unsigned short*)alloc((size_t)M_TOT * QKV_N * 2);
    unsigned short* ctx   = (unsigned short*)alloc((size_t)M_TOT * HIDDEN * 2);

    // prep: 4816896 + 442368 + 147456 + 576 = 5407296 threads -> 21123 blocks
    prep_kernel<<<21123, 256, 0, stream>>>(x, Wq, Wk, Wv, Wp, bq, bk, bv,
                                           xb, wqkv, wpb, biasq);
    // QKV projection: [25088,768] x [2304,768]^T -> bf16 [25088,2304]
    gemm_bt<true><<<dim3(QKV_N / 128, M_TOT / 128), 256, 0, stream>>>(
        xb, wqkv, biasq, (void*)qkv, QKV_N);
    // attention
    attn_kernel<<<BATCH * HEADS, 256, 0, stream>>>(qkv, pos, mask, ctx);
    // output projection: [25088,768] x [768,768]^T -> f32 d_out
    gemm_bt<false><<<dim3(HIDDEN / 128, M_TOT / 128), 256, 0, stream>>>(
        ctx, wpb, bp, d_out, HIDDEN);
}